// Round 1
// baseline (28.187 us; speedup 1.0000x reference)
//
#include <hip/hip_runtime.h>
#include <math.h>

// One thread = one batch element. 4-qubit state = 16 complex64 in registers.
// Wire w corresponds to bit (3-w) of the flat index (wire 0 = MSB), matching
// the reference's (B,2,2,2,2) axis order.

template<int W>
__device__ __forceinline__ void apply_ry(float2* st, float c, float s) {
    constexpr int M = 1 << (3 - W);
    #pragma unroll
    for (int j = 0; j < 16; ++j) {
        if ((j & M) == 0) {
            float2 a0 = st[j], a1 = st[j | M];
            st[j]     = make_float2(c * a0.x - s * a1.x, c * a0.y - s * a1.y);
            st[j | M] = make_float2(s * a0.x + c * a1.x, s * a0.y + c * a1.y);
        }
    }
}

template<int W>
__device__ __forceinline__ void apply_rz(float2* st, float c, float s) {
    // bit=0: multiply by exp(-i t/2) = (c, -s); bit=1: (c, +s)
    constexpr int M = 1 << (3 - W);
    #pragma unroll
    for (int j = 0; j < 16; ++j) {
        float sg = (j & M) ? s : -s;
        float2 a = st[j];
        st[j] = make_float2(c * a.x - sg * a.y, c * a.y + sg * a.x);
    }
}

template<int C, int T>
__device__ __forceinline__ void apply_cnot(float2* st) {
    constexpr int MC = 1 << (3 - C), MT = 1 << (3 - T);
    #pragma unroll
    for (int j = 0; j < 16; ++j) {
        if ((j & MC) != 0 && (j & MT) == 0) {
            float2 tmp = st[j];
            st[j] = st[j | MT];
            st[j | MT] = tmp;
        }
    }
}

template<int A, int Bq>
__device__ __forceinline__ void ansatz(float2* st, const float* pc, const float* ps) {
    apply_ry<A >(st, pc[0], ps[0]);
    apply_rz<A >(st, pc[1], ps[1]);
    apply_ry<Bq>(st, pc[2], ps[2]);
    apply_rz<Bq>(st, pc[3], ps[3]);
    apply_cnot<A, Bq>(st);
    apply_ry<A >(st, pc[4], ps[4]);
    apply_rz<A >(st, pc[5], ps[5]);
    apply_ry<Bq>(st, pc[6], ps[6]);
}

__global__ __launch_bounds__(256) void qsim_kernel(
        const float* __restrict__ patches,
        const float* __restrict__ params,
        float* __restrict__ out, int B) {
    int i = blockIdx.x * blockDim.x + threadIdx.x;
    if (i >= B) return;

    float4 x4 = reinterpret_cast<const float4*>(patches)[i];
    float xs[4] = {x4.x, x4.y, x4.z, x4.w};

    // Encoder: RY(sigmoid(x)*pi) on wire w from |0>, i.e. product state
    float cx[4], sx[4];
    #pragma unroll
    for (int w = 0; w < 4; ++w) {
        float sig = 1.0f / (1.0f + __expf(-xs[w]));
        float half = sig * (0.5f * (float)M_PI);
        __sincosf(half, &sx[w], &cx[w]);
    }

    // Param half-angle sincos (batch-uniform; scalar loads)
    float pc[2][7], ps[2][7];
    #pragma unroll
    for (int l = 0; l < 2; ++l) {
        #pragma unroll
        for (int k = 0; k < 7; ++k) {
            __sincosf(0.5f * params[l * 7 + k], &ps[l][k], &pc[l][k]);
        }
    }

    // Initial encoded state: real product state
    float2 st[16];
    #pragma unroll
    for (int j = 0; j < 16; ++j) {
        float a = ((j >> 3) & 1) ? sx[0] : cx[0];
        float b = ((j >> 2) & 1) ? sx[1] : cx[1];
        float c = ((j >> 1) & 1) ? sx[2] : cx[2];
        float d = ((j >> 0) & 1) ? sx[3] : cx[3];
        st[j] = make_float2(a * b * c * d, 0.0f);
    }

    // Two ansatz layers over pairs (0,1),(1,2),(2,3),(3,0)
    #pragma unroll
    for (int l = 0; l < 2; ++l) {
        ansatz<0, 1>(st, pc[l], ps[l]);
        ansatz<1, 2>(st, pc[l], ps[l]);
        ansatz<2, 3>(st, pc[l], ps[l]);
        ansatz<3, 0>(st, pc[l], ps[l]);
    }

    // MeasureAll PauliZ
    float p[16];
    #pragma unroll
    for (int j = 0; j < 16; ++j)
        p[j] = st[j].x * st[j].x + st[j].y * st[j].y;

    float o[4] = {0.f, 0.f, 0.f, 0.f};
    #pragma unroll
    for (int j = 0; j < 16; ++j) {
        #pragma unroll
        for (int w = 0; w < 4; ++w)
            o[w] += ((j >> (3 - w)) & 1) ? -p[j] : p[j];
    }

    reinterpret_cast<float4*>(out)[i] = make_float4(o[0], o[1], o[2], o[3]);
}

extern "C" void kernel_launch(void* const* d_in, const int* in_sizes, int n_in,
                              void* d_out, int out_size, void* d_ws, size_t ws_size,
                              hipStream_t stream) {
    const float* patches = (const float*)d_in[0];
    const float* params  = (const float*)d_in[1];
    float* out = (float*)d_out;
    int B = in_sizes[0] / 4;
    int block = 256;
    int grid = (B + block - 1) / block;
    qsim_kernel<<<grid, block, 0, stream>>>(patches, params, out, B);
}